// Round 6
// baseline (28853.085 us; speedup 1.0000x reference)
//
#include <hip/hip_runtime.h>
#include <hip/hip_bf16.h>

// ---------------------------------------------------------------------------
// Bidirectional 2-layer LSTM (B=128, T=512, H=256, INPUT=4) + mean-pool + FC.
//
// Round-5: block-local recurrence (no cross-block exchange, verified round-4)
// with REGISTER-RESIDENT weights and 16 waves/block.
//  - 16 blocks = dir(2) x batch-slice(8 of 16 rows), 1024 thr = 16 waves.
//  - wave owns 64 gate-cols (4 gates x 16 units). B-operands loaded ONCE:
//    k_l0 Bf[4][8]=128 VGPRs; k_l1 Bf[4][8]+Bi[4][16]=384 VGPRs.
//  - h(t-1) in swizzled LDS parity double-buffer; one barrier per step.
//  - k_l1 reads h0 (written by k_l0) via plain loads; 67MB -> L3-resident.
//  - no atomics, no flags, no polls, no weight streaming in the loop.
// ws: h0 67.2MB | pooled 256KB | bf16 weights 4MB  (~71.7MB, as round-4).
// ---------------------------------------------------------------------------

typedef __bf16 bf16;
typedef __bf16 bf16x8 __attribute__((ext_vector_type(8)));
typedef float  f32x4  __attribute__((ext_vector_type(4)));
typedef unsigned int u32;
typedef unsigned long long u64;

#define T_SEQ 512
#define BATCH 128
#define HID   256

#define H0_BYTES   67239936ULL                  // bf16 [2][513][128][256]
#define POOL_OFF   H0_BYTES                     // f32 [2][128][256] = 262144 B
#define WB0_OFF    (H0_BYTES + 262144ULL)       // bf16 Whh0 [2][1024][256] = 1MB
#define W1H_OFF    (WB0_OFF + 1048576ULL)       // bf16 Whh1 [2][1024][256] = 1MB
#define W1I_OFF    (W1H_OFF + 1048576ULL)       // bf16 Wih1 [2][1024][512] = 2MB

#define MFMA16(a, b, c) __builtin_amdgcn_mfma_f32_16x16x32_bf16((a), (b), (c), 0, 0, 0)

__device__ __forceinline__ float fsig(float v) {
    return __builtin_amdgcn_rcpf(1.0f + __expf(-v));
}
__device__ __forceinline__ float ftanh(float v) {
    float a = fabsf(v);
    float e = __expf(-2.0f * a);
    float r = (1.0f - e) * __builtin_amdgcn_rcpf(1.0f + e);
    return v < 0.0f ? -r : r;
}

// ---------------------------------------------------------------------------
// k_init: pre-convert recurrent/input weights to bf16 (layouts unchanged).
// ---------------------------------------------------------------------------
__global__ void k_init(const float* __restrict__ whh0, const float* __restrict__ whh1,
                       const float* __restrict__ wih1,
                       bf16* __restrict__ wb0, bf16* __restrict__ w1h,
                       bf16* __restrict__ w1i)
{
    const int t = blockIdx.x * 256 + threadIdx.x;
    const int stride = gridDim.x * 256;
    for (int i = t; i < 2 * 1024 * 256; i += stride) wb0[i] = (bf16)whh0[i];
    for (int i = t; i < 2 * 1024 * 256; i += stride) w1h[i] = (bf16)whh1[i];
    for (int i = t; i < 2 * 1024 * 512; i += stride) w1i[i] = (bf16)wih1[i];
}

// ---------------------------------------------------------------------------
// Layer 0: 16 blocks = slice(8) x dir(2). 1024 thr = 16 waves. Per block:
// M=16 rows, N=1024 (full 4H), K=256. Wave w owns cols
// {tg*256 + w*16 + l15 : tg<4} -> self-contained cell update.
// ---------------------------------------------------------------------------
__global__ __launch_bounds__(1024, 4) void k_l0(
    const float* __restrict__ x, const float* __restrict__ wih,
    const float* __restrict__ bih, const float* __restrict__ bhh,
    const bf16* __restrict__ wb, bf16* __restrict__ h0)
{
    __shared__ __align__(16) char Hp[2 * 8192];    // [parity][16 rows][512B] swizzled

    const int blk = blockIdx.x;
    const int dir = blk & 1, bs = blk >> 1;
    const int tid = threadIdx.x, w = tid >> 6, lane = tid & 63;
    const int l15 = lane & 15, q = lane >> 4;

    // B fragments (register-resident for the whole kernel): 128 VGPRs
    bf16x8 Bf[4][8];
    float biasg[4], wx[4][4];
#pragma unroll
    for (int tg = 0; tg < 4; ++tg) {
        const int n = dir * 1024 + tg * 256 + w * 16 + l15;
        const bf16* wr = wb + (size_t)n * 256 + q * 8;
#pragma unroll
        for (int kt = 0; kt < 8; ++kt) Bf[tg][kt] = *(const bf16x8*)(wr + kt * 32);
        biasg[tg] = bih[n] + bhh[n];
#pragma unroll
        for (int d = 0; d < 4; ++d) wx[tg][d] = wih[(size_t)n * 4 + d];
    }

    ((u64*)Hp)[tid] = 0ULL;                        // zero parity-0 (h(0)=0)
    __syncthreads();

    float c4[4] = {};
#pragma unroll 1
    for (int s = 1; s <= T_SEQ; ++s) {
        const int t_in = dir ? (T_SEQ - s) : (s - 1);
        char* hbp = Hp + ((s - 1) & 1) * 8192;
        char* hbc = Hp + (s & 1) * 8192;

        // gx = bias + x(t).Wih (K=4, VALU; x L1/L2-hot)
        f32x4 xv[4];
#pragma unroll
        for (int r = 0; r < 4; ++r)
            xv[r] = *(const f32x4*)(x + ((size_t)(bs * 16 + q * 4 + r) * T_SEQ + t_in) * 4);
        f32x4 acc[4];
#pragma unroll
        for (int tg = 0; tg < 4; ++tg)
#pragma unroll
            for (int r = 0; r < 4; ++r)
                acc[tg][r] = biasg[tg] + xv[r][0] * wx[tg][0] + xv[r][1] * wx[tg][1]
                                       + xv[r][2] * wx[tg][2] + xv[r][3] * wx[tg][3];

        // A fragments: h(t-1) from swizzled LDS (row=batch row l15)
        bf16x8 av[8];
#pragma unroll
        for (int kt = 0; kt < 8; ++kt)
            av[kt] = *(const bf16x8*)(hbp + l15 * 512 + ((kt * 64 + q * 16) ^ ((l15 & 7) << 4)));

        // h(t-1) x Whh: 32 MFMAs, all operands in regs
#pragma unroll
        for (int kt = 0; kt < 8; ++kt) {
            acc[0] = MFMA16(av[kt], Bf[0][kt], acc[0]);
            acc[1] = MFMA16(av[kt], Bf[1][kt], acc[1]);
            acc[2] = MFMA16(av[kt], Bf[2][kt], acc[2]);
            acc[3] = MFMA16(av[kt], Bf[3][kt], acc[3]);
        }

        // cell update -> swizzled LDS h(t). lane: unit w*16+l15, rows q*4+r
        const int hid2 = (w * 16 + l15) * 2;
#pragma unroll
        for (int r = 0; r < 4; ++r) {
            const float iv = fsig(acc[0][r]);
            const float fv = fsig(acc[1][r]);
            const float gv = ftanh(acc[2][r]);
            const float ov = fsig(acc[3][r]);
            c4[r] = fv * c4[r] + iv * gv;
            const float hv = ov * ftanh(c4[r]);
            const int row = q * 4 + r;
            *(bf16*)(hbc + row * 512 + (hid2 ^ ((row & 7) << 4))) = (bf16)hv;
        }
        __syncthreads();

        // export h(t) to global h0 (plain coalesced stores; k_l1 runs after)
        {
            const int row = tid >> 6, cg = tid & 63;       // 16 rows x 64 x 8B
            const u64 v = *(const u64*)(hbc + row * 512 + ((cg * 8) ^ ((row & 7) << 4)));
            *(u64*)(h0 + ((size_t)(dir * 513 + s) * BATCH + bs * 16 + row) * HID + cg * 4) = v;
        }
    }
}

// ---------------------------------------------------------------------------
// Layer 1: 16 blocks = slice(8) x dir(2). 1024 thr = 16 waves. Per block:
// M=16, N=1024, K=768 = [h1_prev (LDS) | h0f | h0b (global, L3-hot)].
// ALL weights register-resident: Bf 128 + Bi 256 = 384 VGPRs.
// ---------------------------------------------------------------------------
__global__ __launch_bounds__(1024, 4) void k_l1(
    const float* __restrict__ bih1, const float* __restrict__ bhh1,
    const bf16* __restrict__ w1h, const bf16* __restrict__ w1i,
    const bf16* __restrict__ h0, float* __restrict__ pooled)
{
    __shared__ __align__(16) char Hp[2 * 8192];    // h1(t-1) swizzled parity dbuf

    const int blk = blockIdx.x;
    const int dir = blk & 1, bs = blk >> 1;
    const int tid = threadIdx.x, w = tid >> 6, lane = tid & 63;
    const int l15 = lane & 15, q = lane >> 4;

    bf16x8 Bf[4][8];                               // Whh1 slice: 128 VGPRs
    bf16x8 Bi[4][16];                              // Wih1 slice: 256 VGPRs
    float biasw[4];
#pragma unroll
    for (int tg = 0; tg < 4; ++tg) {
        const int n = dir * 1024 + tg * 256 + w * 16 + l15;
        const bf16* ph = w1h + (size_t)n * 256 + q * 8;
        const bf16* pi = w1i + (size_t)n * 512 + q * 8;
#pragma unroll
        for (int kt = 0; kt < 8; ++kt)  Bf[tg][kt] = *(const bf16x8*)(ph + kt * 32);
#pragma unroll
        for (int kt = 0; kt < 16; ++kt) Bi[tg][kt] = *(const bf16x8*)(pi + kt * 32);
        biasw[tg] = bih1[n] + bhh1[n];
    }

    ((u64*)Hp)[tid] = 0ULL;
    __syncthreads();

    float c4[4] = {};
    float pool[4] = {};
#pragma unroll 1
    for (int s = 1; s <= T_SEQ; ++s) {
        const int slotf = dir ? (513 - s) : s;     // h0 fwd slot for time t
        const int slotb = dir ? s : (513 - s);     // h0 bwd slot for time t
        char* hbp = Hp + ((s - 1) & 1) * 8192;
        char* hbc = Hp + (s & 1) * 8192;

        // issue h0-fwd A loads early (global, L3-hot)
        const bf16* f0 = h0 + ((size_t)slotf * BATCH + bs * 16 + l15) * HID + q * 8;
        const bf16* b0 = h0 + ((size_t)(513 + slotb) * BATCH + bs * 16 + l15) * HID + q * 8;
        bf16x8 avf[8];
#pragma unroll
        for (int kt = 0; kt < 8; ++kt) avf[kt] = *(const bf16x8*)(f0 + kt * 32);

        // h1(t-1) from LDS
        bf16x8 av1[8];
#pragma unroll
        for (int kt = 0; kt < 8; ++kt)
            av1[kt] = *(const bf16x8*)(hbp + l15 * 512 + ((kt * 64 + q * 16) ^ ((l15 & 7) << 4)));

        f32x4 acc[4];
#pragma unroll
        for (int tg = 0; tg < 4; ++tg) {
            acc[tg][0] = biasw[tg]; acc[tg][1] = biasw[tg];
            acc[tg][2] = biasw[tg]; acc[tg][3] = biasw[tg];
        }

        // h1_prev x Whh1 (LDS operands, fast)
#pragma unroll
        for (int kt = 0; kt < 8; ++kt) {
            acc[0] = MFMA16(av1[kt], Bf[0][kt], acc[0]);
            acc[1] = MFMA16(av1[kt], Bf[1][kt], acc[1]);
            acc[2] = MFMA16(av1[kt], Bf[2][kt], acc[2]);
            acc[3] = MFMA16(av1[kt], Bf[3][kt], acc[3]);
        }

        // issue h0-bwd loads here (hides under h0f MFMAs, caps VGPR liveness)
        bf16x8 avb[8];
#pragma unroll
        for (int kt = 0; kt < 8; ++kt) avb[kt] = *(const bf16x8*)(b0 + kt * 32);

        // h0-fwd x Wih1[:, 0:256]
#pragma unroll
        for (int kt = 0; kt < 8; ++kt) {
            acc[0] = MFMA16(avf[kt], Bi[0][kt], acc[0]);
            acc[1] = MFMA16(avf[kt], Bi[1][kt], acc[1]);
            acc[2] = MFMA16(avf[kt], Bi[2][kt], acc[2]);
            acc[3] = MFMA16(avf[kt], Bi[3][kt], acc[3]);
        }
        // h0-bwd x Wih1[:, 256:512]
#pragma unroll
        for (int kt = 0; kt < 8; ++kt) {
            acc[0] = MFMA16(avb[kt], Bi[0][8 + kt], acc[0]);
            acc[1] = MFMA16(avb[kt], Bi[1][8 + kt], acc[1]);
            acc[2] = MFMA16(avb[kt], Bi[2][8 + kt], acc[2]);
            acc[3] = MFMA16(avb[kt], Bi[3][8 + kt], acc[3]);
        }

        // cell update + pool + h1(t) -> swizzled LDS
        const int hid2 = (w * 16 + l15) * 2;
#pragma unroll
        for (int r = 0; r < 4; ++r) {
            const float iv = fsig(acc[0][r]);
            const float fv = fsig(acc[1][r]);
            const float gv = ftanh(acc[2][r]);
            const float ov = fsig(acc[3][r]);
            c4[r] = fv * c4[r] + iv * gv;
            const float hv = ov * ftanh(c4[r]);
            pool[r] += hv;
            const int row = q * 4 + r;
            *(bf16*)(hbc + row * 512 + (hid2 ^ ((row & 7) << 4))) = (bf16)hv;
        }
        __syncthreads();
    }

    // mean-pool epilogue: lane (q,l15,w): rows q*4+r, unit w*16+l15
#pragma unroll
    for (int r = 0; r < 4; ++r)
        pooled[((size_t)dir * BATCH + bs * 16 + q * 4 + r) * HID + (w * 16 + l15)] =
            pool[r] * (1.0f / 512.0f);
}

// ---------------------------------------------------------------------------
__global__ void k_fc(const float* __restrict__ pooled, const float* __restrict__ fcw,
                     const float* __restrict__ fcb, float* __restrict__ out)
{
    const int b = blockIdx.x;            // 128 blocks, 64 threads
    const int lane = threadIdx.x;
    float s0 = 0.f, s1 = 0.f;
#pragma unroll
    for (int jj = 0; jj < 8; ++jj) {
        const int jx = lane + jj * 64;   // 0..511
        const float p = (jx < 256) ? pooled[(size_t)b * 256 + jx]
                                   : pooled[32768 + (size_t)b * 256 + (jx - 256)];
        s0 += p * fcw[jx];
        s1 += p * fcw[512 + jx];
    }
#pragma unroll
    for (int off = 32; off > 0; off >>= 1) {
        s0 += __shfl_down(s0, off);
        s1 += __shfl_down(s1, off);
    }
    if (lane == 0) {
        out[b * 2 + 0] = s0 + fcb[0];
        out[b * 2 + 1] = s1 + fcb[1];
    }
}

// ---------------------------------------------------------------------------
extern "C" void kernel_launch(void* const* d_in, const int* in_sizes, int n_in,
                              void* d_out, int out_size, void* d_ws, size_t ws_size,
                              hipStream_t stream)
{
    const float* x    = (const float*)d_in[0];
    const float* wih0 = (const float*)d_in[1];
    const float* whh0 = (const float*)d_in[2];
    const float* bih0 = (const float*)d_in[3];
    const float* bhh0 = (const float*)d_in[4];
    const float* wih1 = (const float*)d_in[5];
    const float* whh1 = (const float*)d_in[6];
    const float* bih1 = (const float*)d_in[7];
    const float* bhh1 = (const float*)d_in[8];
    const float* fcw  = (const float*)d_in[9];
    const float* fcb  = (const float*)d_in[10];
    float* out = (float*)d_out;

    char* ws = (char*)d_ws;
    bf16* h0      = (bf16*)ws;
    float* pooled = (float*)(ws + POOL_OFF);
    bf16* wb0     = (bf16*)(ws + WB0_OFF);
    bf16* w1h     = (bf16*)(ws + W1H_OFF);
    bf16* w1i     = (bf16*)(ws + W1I_OFF);

    k_init<<<dim3(512), dim3(256), 0, stream>>>(whh0, whh1, wih1, wb0, w1h, w1i);
    k_l0<<<dim3(16), dim3(1024), 0, stream>>>(x, wih0, bih0, bhh0, wb0, h0);
    k_l1<<<dim3(16), dim3(1024), 0, stream>>>(bih1, bhh1, w1h, w1i, h0, pooled);
    k_fc<<<dim3(128), dim3(64), 0, stream>>>(pooled, fcw, fcb, out);
}

// Round 9
// 14224.051 us; speedup vs baseline: 2.0285x; 2.0285x over previous
//
#include <hip/hip_runtime.h>
#include <hip/hip_bf16.h>

// ---------------------------------------------------------------------------
// Bidirectional 2-layer LSTM (B=128, T=512, H=256, INPUT=4) + mean-pool + FC.
//
// Round-9: baseline-proven exchange (agent-scope relaxed atomics, flag after
// __syncthreads-drain), restructured for LOW FAN-IN and MORE WORK PER BLOCK:
//  - k_l0: 16 blocks = dir(2) x bh(2) x g(4). Cluster (dir,bh) has 4
//    producers (was 16). Block: M=64, N=256 (64 units x 4 gates), K=256.
//    8 waves = ug(4) x mh(2); resident Whh frags 128 VGPR/wave.
//  - k_l1: 32 blocks = dir(2) x bq(2) x g(8). Cluster (dir,bq) has 8
//    producers (was 16). Block: M=64, N=128 (32 units x 4 gates), K=768.
//    8 waves = gate(4) x uh(2); 24 resident frags = 96 VGPR (baseline);
//    h0 GEMM pre-poll; h1_prev staged to LDS; LDS gate exchange.
//  - Numerics and protocol identical to the verified round-0 kernel.
// ---------------------------------------------------------------------------

typedef __bf16 bf16;
typedef __bf16 bf16x8 __attribute__((ext_vector_type(8)));
typedef float  f32x4  __attribute__((ext_vector_type(4)));
typedef unsigned int u32;
typedef unsigned long long u64;
typedef u64 u64x2 __attribute__((ext_vector_type(2)));

#define T_SEQ 512
#define BATCH 128
#define HID   256

// ws layout (bytes)
#define H0_BYTES   67239936ULL                  // bf16 [2][513][128][256]
#define H1_BYTES   262144ULL                    // bf16 [2][2][128][256] ring
#define POOL_BYTES 262144ULL                    // f32  [2][128][256]
#define FL0_OFF    (H0_BYTES + H1_BYTES + POOL_BYTES)
#define FL1_OFF    (FL0_OFF + 4096ULL)

#define MFMA16(a, b, c) __builtin_amdgcn_mfma_f32_16x16x32_bf16((a), (b), (c), 0, 0, 0)
#define AL(p)     __hip_atomic_load((p), __ATOMIC_RELAXED, __HIP_MEMORY_SCOPE_AGENT)
#define AS(p, v)  __hip_atomic_store((p), (v), __ATOMIC_RELAXED, __HIP_MEMORY_SCOPE_AGENT)

__device__ __forceinline__ float fsig(float v) {
    return __builtin_amdgcn_rcpf(1.0f + __expf(-v));
}
__device__ __forceinline__ float ftanh(float v) {
    float a = fabsf(v);
    float e = __expf(-2.0f * a);
    float r = (1.0f - e) * __builtin_amdgcn_rcpf(1.0f + e);
    return v < 0.0f ? -r : r;
}

// ---------------------------------------------------------------------------
__global__ void k_init(unsigned int* ws_u, int* flags0, int* flags1) {
    const int t = blockIdx.x * 256 + threadIdx.x;       // 0..16383
    ws_u[t] = 0u;                                       // h0[0][slot0]
    ws_u[(size_t)513 * 16384 + t] = 0u;                 // h0[1][slot0]
    unsigned int* h1u = ws_u + (H0_BYTES / 4);
    h1u[t] = 0u;                                        // h1 dir0 parity0
    h1u[32768 + t] = 0u;                                // h1 dir1 parity0
    if (t < 1024) flags0[t] = 0;
    if (t < 2048) flags1[t] = 0;
}

// ---------------------------------------------------------------------------
// Layer 0: grid 16 = dir(2) x bh(2) x g(4). 512 thr = 8 waves.
// Block: rows bh*64+[0,64), units g*64+[0,64), all 4 gates, K=256.
// Wave (ug,mh): units g*64+ug*16+[0,16), rows bh*64+mh*32+[0,32).
// Cluster (dir,bh): 4 producer flags.
// ---------------------------------------------------------------------------
__global__ __launch_bounds__(512, 2) void k_l0(
    const float* __restrict__ x, const float* __restrict__ wih,
    const float* __restrict__ whh, const float* __restrict__ bih,
    const float* __restrict__ bhh, bf16* __restrict__ h0,
    int* __restrict__ flags)
{
    __shared__ __align__(16) bf16 Hs[64][72];          // [row][unit], pad 72

    const int blk = blockIdx.x;
    const int dir = blk >> 3, bh = (blk >> 2) & 1, g = blk & 3;
    const int tid = threadIdx.x, wave = tid >> 6, lane = tid & 63;
    const int l15 = lane & 15, q = lane >> 4;
    const int ug = wave & 3, mh = wave >> 2;
    const int j = g * 64 + ug * 16 + l15;              // hidden unit (B col)

    // Resident B fragments: Bf[gate][kt] = 128 VGPR (verified pattern).
    bf16x8 Bf[4][8];
    float biasg[4], wx[4][4];
#pragma unroll
    for (int tg = 0; tg < 4; ++tg) {
        const int n = dir * 1024 + tg * 256 + j;
        const float* wr = whh + (size_t)n * 256 + q * 8;
#pragma unroll
        for (int kt = 0; kt < 8; ++kt) {
            f32x4 aa = *(const f32x4*)(wr + kt * 32);
            f32x4 bb = *(const f32x4*)(wr + kt * 32 + 4);
            bf16x8 f;
            f[0] = (bf16)aa[0]; f[1] = (bf16)aa[1]; f[2] = (bf16)aa[2]; f[3] = (bf16)aa[3];
            f[4] = (bf16)bb[0]; f[5] = (bf16)bb[1]; f[6] = (bf16)bb[2]; f[7] = (bf16)bb[3];
            Bf[tg][kt] = f;
        }
        biasg[tg] = bih[n] + bhh[n];
#pragma unroll
        for (int d = 0; d < 4; ++d) wx[tg][d] = wih[(size_t)n * 4 + d];
    }

    float c4[2][4] = {};
    const int rbase = bh * 64 + mh * 32;               // block-row base (this wave)
    int* fgrp = flags + (dir * 2 + bh) * 64;           // 4 flags, stride 16
    int budget = 30000000;

#pragma unroll 1
    for (int s = 1; s <= T_SEQ; ++s) {
        const int t_in = dir ? (T_SEQ - s) : (s - 1);

        // --- pre-poll: bias + x(t).Wih (non-racy, cached loads) ---
        f32x4 acc[4][2];
#pragma unroll
        for (int Mt = 0; Mt < 2; ++Mt) {
            f32x4 xv[4];
#pragma unroll
            for (int r = 0; r < 4; ++r)
                xv[r] = *(const f32x4*)(x + ((size_t)(rbase + Mt * 16 + q * 4 + r) * T_SEQ
                                             + t_in) * 4);
#pragma unroll
            for (int tg = 0; tg < 4; ++tg)
#pragma unroll
                for (int r = 0; r < 4; ++r)
                    acc[tg][Mt][r] = biasg[tg]
                        + xv[r][0] * wx[tg][0] + xv[r][1] * wx[tg][1]
                        + xv[r][2] * wx[tg][2] + xv[r][3] * wx[tg][3];
        }

        // --- poll the 4 producers of this cluster ---
        if (lane < 4) {
            const int need = s - 1;
            while (AL(fgrp + lane * 16) < need) {
                if (--budget < 0) break;
            }
        }
        asm volatile("" ::: "memory");

        // --- racy A loads + MFMA, per M-tile (keeps VGPR in budget) ---
#pragma unroll
        for (int Mt = 0; Mt < 2; ++Mt) {
            const u64* hsrc = (const u64*)(h0 + ((size_t)(dir * 513 + (s - 1)) * BATCH
                                                 + rbase + Mt * 16 + l15) * HID) + q * 2;
            u64 av[16];
#pragma unroll
            for (int kt = 0; kt < 8; ++kt) {
                av[2 * kt]     = AL(hsrc + kt * 8);
                av[2 * kt + 1] = AL(hsrc + kt * 8 + 1);
            }
#pragma unroll
            for (int kt = 0; kt < 8; ++kt) {
                u64x2 t2; t2[0] = av[2 * kt]; t2[1] = av[2 * kt + 1];
                const bf16x8 A = __builtin_bit_cast(bf16x8, t2);
                acc[0][Mt] = MFMA16(A, Bf[0][kt], acc[0][Mt]);
                acc[1][Mt] = MFMA16(A, Bf[1][kt], acc[1][Mt]);
                acc[2][Mt] = MFMA16(A, Bf[2][kt], acc[2][Mt]);
                acc[3][Mt] = MFMA16(A, Bf[3][kt], acc[3][Mt]);
            }
        }

        // --- cell update -> LDS repack ---
#pragma unroll
        for (int Mt = 0; Mt < 2; ++Mt)
#pragma unroll
            for (int r = 0; r < 4; ++r) {
                const float iv = fsig(acc[0][Mt][r]);
                const float fv = fsig(acc[1][Mt][r]);
                const float gv = ftanh(acc[2][Mt][r]);
                const float ov = fsig(acc[3][Mt][r]);
                c4[Mt][r] = fv * c4[Mt][r] + iv * gv;
                const float hv = ov * ftanh(c4[Mt][r]);
                Hs[mh * 32 + Mt * 16 + q * 4 + r][ug * 16 + l15] = (bf16)hv;
            }
        __syncthreads();

        // --- export 64x64 h-slice: 2 x 8B agent-atomic stores per thread ---
        {
            const int row = tid >> 3, u0 = (tid & 7) * 8;
            u64* dst = (u64*)(h0 + ((size_t)(dir * 513 + s) * BATCH + bh * 64 + row) * HID
                              + g * 64 + u0);
            AS(dst,     *(const u64*)&Hs[row][u0]);
            AS(dst + 1, *(const u64*)&Hs[row][u0 + 4]);
        }
        __syncthreads();                       // drains vmcnt before flag
        if (tid == 0) AS(fgrp + g * 16, s);
    }
}

// ---------------------------------------------------------------------------
// Layer 1: grid 32 = dir(2) x bq(2) x g(8). 512 thr = 8 waves.
// Block: rows bq*64+[0,64), units g*32+[0,32), K=768 ([h1_prev|h0f|h0b]).
// Wave (gate,uh): one gate, units g*32+uh*16+[0,16), all 64 rows (4 Mt).
// Cluster (dir,bq): 8 producer flags.
// ---------------------------------------------------------------------------
__global__ __launch_bounds__(512, 2) void k_l1(
    const float* __restrict__ wih1, const float* __restrict__ whh1,
    const float* __restrict__ bih1, const float* __restrict__ bhh1,
    bf16* __restrict__ h0, bf16* __restrict__ h1,
    float* __restrict__ pooled, int* __restrict__ flags)
{
    __shared__ float Gs[4][64][33];                    // gate exchange (pad 33)
    __shared__ __align__(16) bf16 Hs[64][40];          // h repack (pad 40)
    __shared__ __align__(16) bf16 As1[64][264];        // h1_prev stage (pad 264)

    const int blk = blockIdx.x;
    const int dir = blk >> 4, bq = (blk >> 3) & 1, g = blk & 7;
    const int tid = threadIdx.x, wave = tid >> 6, lane = tid & 63;
    const int l15 = lane & 15, q = lane >> 4;
    const int gate = wave & 3, uh = wave >> 2;
    const int n = dir * 1024 + gate * 256 + g * 32 + uh * 16 + l15;

    // Resident B fragments: 24 x 4 VGPR = 96 VGPRs (baseline pattern).
    bf16x8 Bf[24];
#pragma unroll
    for (int kt = 0; kt < 24; ++kt) {
        const int k = kt * 32 + q * 8;
        const float* src = (kt < 8) ? (whh1 + (size_t)n * 256 + k)
                                    : (wih1 + (size_t)n * 512 + (k - 256));
        f32x4 aa = *(const f32x4*)src;
        f32x4 bb = *(const f32x4*)(src + 4);
        bf16x8 f;
        f[0] = (bf16)aa[0]; f[1] = (bf16)aa[1]; f[2] = (bf16)aa[2]; f[3] = (bf16)aa[3];
        f[4] = (bf16)bb[0]; f[5] = (bf16)bb[1]; f[6] = (bf16)bb[2]; f[7] = (bf16)bb[3];
        Bf[kt] = f;
    }
    const float biasw = bih1[n] + bhh1[n];
    const int r0 = tid >> 5, colu = tid & 31;     // update: rows r0+16rr, unit colu
    float cst[4] = {}, pool[4] = {};
    int* fgrp = flags + (dir * 2 + bq) * 128;     // 8 flags, stride 16
    int budget = 30000000;

#pragma unroll 1
    for (int s = 1; s <= T_SEQ; ++s) {
        const int slotf = dir ? (513 - s) : s;     // h0 fwd slot for time t
        const int slotb = dir ? s : (513 - s);     // h0 bwd slot for time t

        // --- pre-poll: h0 contribution (non-racy, cached; cross-dispatch) ---
        f32x4 acc[4];
#pragma unroll
        for (int Mt = 0; Mt < 4; ++Mt) {
            acc[Mt][0] = biasw; acc[Mt][1] = biasw;
            acc[Mt][2] = biasw; acc[Mt][3] = biasw;
        }
        const bf16* f0 = h0 + ((size_t)slotf * BATCH + bq * 64 + l15) * HID + q * 8;
        const bf16* b0 = h0 + ((size_t)(513 + slotb) * BATCH + bq * 64 + l15) * HID + q * 8;
#pragma unroll
        for (int kt = 0; kt < 8; ++kt) {
#pragma unroll
            for (int Mt = 0; Mt < 4; ++Mt) {
                const bf16x8 af = *(const bf16x8*)(f0 + (size_t)Mt * 16 * HID + kt * 32);
                acc[Mt] = MFMA16(af, Bf[8 + kt], acc[Mt]);
            }
        }
#pragma unroll
        for (int kt = 0; kt < 8; ++kt) {
#pragma unroll
            for (int Mt = 0; Mt < 4; ++Mt) {
                const bf16x8 ab = *(const bf16x8*)(b0 + (size_t)Mt * 16 * HID + kt * 32);
                acc[Mt] = MFMA16(ab, Bf[16 + kt], acc[Mt]);
            }
        }

        // --- poll the 8 producers of this cluster ---
        if (lane < 8) {
            const int need = s - 1;
            while (AL(fgrp + lane * 16) < need) {
                if (--budget < 0) break;
            }
        }
        asm volatile("" ::: "memory");

        // --- stage racy h1_prev [64][256] into LDS (atomic u64 loads) ---
        {
            const u64* hb = (const u64*)(h1 + ((size_t)(dir * 2 + ((s - 1) & 1)) * BATCH
                                               + bq * 64) * HID);
#pragma unroll
            for (int i = 0; i < 4; ++i) {
                const int chunk = tid + 512 * i;         // 0..2047 (16B chunks)
                const int row = chunk >> 5, cc = chunk & 31;
                const u64 lo = AL(hb + (size_t)row * 64 + cc * 2);
                const u64 hi = AL(hb + (size_t)row * 64 + cc * 2 + 1);
                u64x2 t2; t2[0] = lo; t2[1] = hi;
                *(bf16x8*)(&As1[row][cc * 8]) = __builtin_bit_cast(bf16x8, t2);
            }
        }
        __syncthreads();

        // --- h1_prev GEMM from LDS: 4 M-tiles x 8 K-steps ---
#pragma unroll
        for (int kt = 0; kt < 8; ++kt) {
#pragma unroll
            for (int Mt = 0; Mt < 4; ++Mt) {
                const bf16x8 a = *(const bf16x8*)(&As1[Mt * 16 + l15][kt * 32 + q * 8]);
                acc[Mt] = MFMA16(a, Bf[kt], acc[Mt]);
            }
        }

        // --- gate exchange via LDS ---
#pragma unroll
        for (int Mt = 0; Mt < 4; ++Mt)
#pragma unroll
            for (int r = 0; r < 4; ++r)
                Gs[gate][Mt * 16 + q * 4 + r][uh * 16 + l15] = acc[Mt][r];
        __syncthreads();

        // --- cell update: rows r0+16rr of unit colu ---
#pragma unroll
        for (int rr = 0; rr < 4; ++rr) {
            const int r = r0 + rr * 16;
            const float iv = fsig(Gs[0][r][colu]);
            const float fv = fsig(Gs[1][r][colu]);
            const float gv = ftanh(Gs[2][r][colu]);
            const float ov = fsig(Gs[3][r][colu]);
            cst[rr] = fv * cst[rr] + iv * gv;
            const float hv = ov * ftanh(cst[rr]);
            pool[rr] += hv;
            Hs[r][colu] = (bf16)hv;
        }
        __syncthreads();

        // --- store 64x32 h1-slice: one 8B agent-atomic store per thread ---
        {
            const int row = tid >> 3, c4u = (tid & 7) * 4;
            u64* dst = (u64*)(h1 + ((size_t)(dir * 2 + (s & 1)) * BATCH + bq * 64 + row) * HID
                              + g * 32 + c4u);
            AS(dst, *(const u64*)&Hs[row][c4u]);
        }
        __syncthreads();                       // drains vmcnt before flag
        if (tid == 0) AS(fgrp + g * 16, s);
    }

    // mean pool epilogue
#pragma unroll
    for (int rr = 0; rr < 4; ++rr) {
        const int row = r0 + rr * 16;
        pooled[((size_t)dir * BATCH + bq * 64 + row) * HID + g * 32 + colu] =
            pool[rr] * (1.0f / 512.0f);
    }
}

// ---------------------------------------------------------------------------
__global__ void k_fc(const float* __restrict__ pooled, const float* __restrict__ fcw,
                     const float* __restrict__ fcb, float* __restrict__ out)
{
    const int b = blockIdx.x;            // 128 blocks, 64 threads
    const int lane = threadIdx.x;
    float s0 = 0.f, s1 = 0.f;
#pragma unroll
    for (int jj = 0; jj < 8; ++jj) {
        const int jx = lane + jj * 64;   // 0..511
        const float p = (jx < 256) ? pooled[(size_t)b * 256 + jx]
                                   : pooled[32768 + (size_t)b * 256 + (jx - 256)];
        s0 += p * fcw[jx];
        s1 += p * fcw[512 + jx];
    }
#pragma unroll
    for (int off = 32; off > 0; off >>= 1) {
        s0 += __shfl_down(s0, off);
        s1 += __shfl_down(s1, off);
    }
    if (lane == 0) {
        out[b * 2 + 0] = s0 + fcb[0];
        out[b * 2 + 1] = s1 + fcb[1];
    }
}

// ---------------------------------------------------------------------------
extern "C" void kernel_launch(void* const* d_in, const int* in_sizes, int n_in,
                              void* d_out, int out_size, void* d_ws, size_t ws_size,
                              hipStream_t stream)
{
    const float* x    = (const float*)d_in[0];
    const float* wih0 = (const float*)d_in[1];
    const float* whh0 = (const float*)d_in[2];
    const float* bih0 = (const float*)d_in[3];
    const float* bhh0 = (const float*)d_in[4];
    const float* wih1 = (const float*)d_in[5];
    const float* whh1 = (const float*)d_in[6];
    const float* bih1 = (const float*)d_in[7];
    const float* bhh1 = (const float*)d_in[8];
    const float* fcw  = (const float*)d_in[9];
    const float* fcb  = (const float*)d_in[10];
    float* out = (float*)d_out;

    char* ws = (char*)d_ws;
    bf16* h0      = (bf16*)ws;
    bf16* h1      = (bf16*)(ws + H0_BYTES);
    float* pooled = (float*)(ws + H0_BYTES + H1_BYTES);
    int* flags0   = (int*)(ws + FL0_OFF);
    int* flags1   = (int*)(ws + FL1_OFF);

    k_init<<<dim3(64), dim3(256), 0, stream>>>((unsigned int*)ws, flags0, flags1);
    k_l0<<<dim3(16), dim3(512), 0, stream>>>(x, wih0, whh0, bih0, bhh0, h0, flags0);
    k_l1<<<dim3(32), dim3(512), 0, stream>>>(wih1, whh1, bih1, bhh1, h0, h1, pooled, flags1);
    k_fc<<<dim3(128), dim3(64), 0, stream>>>(pooled, fcw, fcb, out);
}

// Round 10
// 4881.142 us; speedup vs baseline: 5.9111x; 2.9141x over previous
//
#include <hip/hip_runtime.h>
#include <hip/hip_bf16.h>

// ---------------------------------------------------------------------------
// Bidirectional 2-layer LSTM (B=128, T=512, H=256, INPUT=4) + mean-pool + FC.
//
// Round-10: EXACT verified round-0 baseline (4864us) + one knob:
//   __attribute__((amdgpu_waves_per_eu(1,1))) on k_l0/k_l1.
// Theory: baseline VGPR_Count (k_l1=92 < Bf[24]'s 96; k_l0=136 ~= Bf's 128)
// proves the backend rematerialized the "resident" weight fragments to chase
// occupancy -> every step re-streams B from L2 on the critical chain.
// Both kernels run ~2 waves/CU anyway; capping waves/EU at 1 unlocks the
// 512-VGPR budget so weights become truly register-resident.
// ---------------------------------------------------------------------------

typedef __bf16 bf16;
typedef __bf16 bf16x8 __attribute__((ext_vector_type(8)));
typedef float  f32x4  __attribute__((ext_vector_type(4)));
typedef unsigned int u32;
typedef unsigned long long u64;
typedef u64 u64x2 __attribute__((ext_vector_type(2)));

#define T_SEQ 512
#define BATCH 128
#define HID   256

// ws layout (bytes)
#define H0_BYTES   67239936ULL                  // bf16 [2][513][128][256]
#define H1_BYTES   262144ULL                    // bf16 [2][2][128][256] ring
#define POOL_BYTES 262144ULL                    // f32  [2][128][256]
#define FL0_OFF    (H0_BYTES + H1_BYTES + POOL_BYTES)
#define FL1_OFF    (FL0_OFF + 4096ULL)          // flags0: 4 grp x 16 x 16 ints

#define MFMA16(a, b, c) __builtin_amdgcn_mfma_f32_16x16x32_bf16((a), (b), (c), 0, 0, 0)
#define AL(p)     __hip_atomic_load((p), __ATOMIC_RELAXED, __HIP_MEMORY_SCOPE_AGENT)
#define AS(p, v)  __hip_atomic_store((p), (v), __ATOMIC_RELAXED, __HIP_MEMORY_SCOPE_AGENT)

__device__ __forceinline__ float fsig(float v) {
    return __builtin_amdgcn_rcpf(1.0f + __expf(-v));
}
__device__ __forceinline__ float ftanh(float v) {
    float a = fabsf(v);
    float e = __expf(-2.0f * a);
    float r = (1.0f - e) * __builtin_amdgcn_rcpf(1.0f + e);
    return v < 0.0f ? -r : r;
}

// ---------------------------------------------------------------------------
__global__ void k_init(unsigned int* ws_u, int* flags0, int* flags1) {
    const int t = blockIdx.x * 256 + threadIdx.x;       // 0..16383
    ws_u[t] = 0u;                                       // h0[0][slot0]
    ws_u[(size_t)513 * 16384 + t] = 0u;                 // h0[1][slot0]
    unsigned int* h1u = ws_u + (H0_BYTES / 4);
    h1u[t] = 0u;                                        // h1 dir0 parity0
    h1u[32768 + t] = 0u;                                // h1 dir1 parity0
    if (t < 1024) flags0[t] = 0;
    if (t < 2048) flags1[t] = 0;
}

// ---------------------------------------------------------------------------
// Layer 0: grid 64 = dir(2) x batch-half(2) x gate-group(16). 256 thr/block.
// M=64 rows, N=64 cols (i,f,g,o of 16 hidden units), K=256. Waves split M.
// Weights: 4x8 B-fragments = 128 VGPRs, loaded once (now truly resident).
// ---------------------------------------------------------------------------
__global__ __launch_bounds__(256, 1)
__attribute__((amdgpu_waves_per_eu(1, 1)))
void k_l0(
    const float* __restrict__ x, const float* __restrict__ wih,
    const float* __restrict__ whh, const float* __restrict__ bih,
    const float* __restrict__ bhh, bf16* __restrict__ h0,
    int* __restrict__ flags)
{
    __shared__ __align__(16) bf16 Hs[64][20];          // pad 20: conflict-free

    const int blk = blockIdx.x;
    const int dir = blk >> 5, bh = (blk >> 4) & 1, g = blk & 15;
    const int tid = threadIdx.x, wave = tid >> 6, lane = tid & 63;
    const int l15 = lane & 15, q = lane >> 4;
    const int j = g * 16 + l15;                 // hidden unit (column)

    // B fragments: Bf[gate][kt], n = gate*256 + j, k = kt*32 + q*8 .. +8
    bf16x8 Bf[4][8];
#pragma unroll
    for (int tg = 0; tg < 4; ++tg) {
        const float* wr = whh + ((size_t)(dir * 1024 + tg * 256 + j)) * 256 + q * 8;
#pragma unroll
        for (int kt = 0; kt < 8; ++kt) {
            f32x4 aa = *(const f32x4*)(wr + kt * 32);
            f32x4 bb = *(const f32x4*)(wr + kt * 32 + 4);
            bf16x8 f;
            f[0] = (bf16)aa[0]; f[1] = (bf16)aa[1]; f[2] = (bf16)aa[2]; f[3] = (bf16)aa[3];
            f[4] = (bf16)bb[0]; f[5] = (bf16)bb[1]; f[6] = (bf16)bb[2]; f[7] = (bf16)bb[3];
            Bf[tg][kt] = f;
        }
    }
    float biasg[4], wx[4][4];
#pragma unroll
    for (int tg = 0; tg < 4; ++tg) {
        const int n = dir * 1024 + tg * 256 + j;
        biasg[tg] = bih[n] + bhh[n];
#pragma unroll
        for (int d2 = 0; d2 < 4; ++d2) wx[tg][d2] = wih[(size_t)n * 4 + d2];
    }

    float c4[4] = {0.f, 0.f, 0.f, 0.f};
    const int arow  = bh * 64 + wave * 16 + l15;   // A-operand row (load)
    const int lrow0 = wave * 16 + q * 4;           // local C rows base
    const int mrow0 = bh * 64 + lrow0;             // global C rows base
    const int srow = tid >> 2, scg = (tid & 3) * 4; // 8B-store mapping
    int* fgrp = flags + (dir * 2 + bh) * 256;      // 16 flags, stride 16
    int budget = 30000000;

#pragma unroll 1
    for (int s = 1; s <= T_SEQ; ++s) {
        const int t_in = dir ? (T_SEQ - s) : (s - 1);

        // --- pre-poll: bias + x(t).w_ih (non-racy, cached loads) ---
        f32x4 xv[4];
#pragma unroll
        for (int r = 0; r < 4; ++r)
            xv[r] = *(const f32x4*)(x + ((size_t)(mrow0 + r) * T_SEQ + t_in) * 4);
        f32x4 acc[4];
#pragma unroll
        for (int tg = 0; tg < 4; ++tg) {
#pragma unroll
            for (int r = 0; r < 4; ++r) {
                acc[tg][r] = biasg[tg] + xv[r][0] * wx[tg][0] + xv[r][1] * wx[tg][1]
                                       + xv[r][2] * wx[tg][2] + xv[r][3] * wx[tg][3];
            }
        }

        // --- poll producers (per-wave; relaxed agent loads -> MALL) ---
        if (lane < 16) {
            const int need = s - 1;
            while (AL(fgrp + lane * 16) < need) {
                if (--budget < 0) break;
            }
        }
        asm volatile("" ::: "memory");

        // --- racy A loads: relaxed agent atomic u64 (bypass, from MALL) ---
        const u64* hsrc = (const u64*)(h0 + ((size_t)(dir * 513 + (s - 1)) * BATCH + arow) * HID)
                          + q * 2;
        u64 av[16];
#pragma unroll
        for (int kt = 0; kt < 8; ++kt) {
            av[2 * kt]     = AL(hsrc + kt * 8);
            av[2 * kt + 1] = AL(hsrc + kt * 8 + 1);
        }
#pragma unroll
        for (int kt = 0; kt < 8; ++kt) {
            u64x2 t2; t2[0] = av[2 * kt]; t2[1] = av[2 * kt + 1];
            const bf16x8 A = __builtin_bit_cast(bf16x8, t2);
            acc[0] = MFMA16(A, Bf[0][kt], acc[0]);
            acc[1] = MFMA16(A, Bf[1][kt], acc[1]);
            acc[2] = MFMA16(A, Bf[2][kt], acc[2]);
            acc[3] = MFMA16(A, Bf[3][kt], acc[3]);
        }

        // --- cell update -> LDS repack ---
#pragma unroll
        for (int r = 0; r < 4; ++r) {
            const float iv = fsig(acc[0][r]);
            const float fv = fsig(acc[1][r]);
            const float gv = ftanh(acc[2][r]);
            const float ov = fsig(acc[3][r]);
            c4[r] = fv * c4[r] + iv * gv;
            const float hv = ov * ftanh(c4[r]);
            Hs[lrow0 + r][l15] = (bf16)hv;
        }
        __syncthreads();
        // 8B agent-atomic store per thread -> MALL
        {
            const u64 hv8 = *(const u64*)&Hs[srow][scg];
            u64* dst = (u64*)(h0 + ((size_t)(dir * 513 + s) * BATCH + bh * 64 + srow) * HID
                              + g * 16 + scg);
            AS(dst, hv8);
        }
        __syncthreads();                       // drains vmcnt before flag
        if (tid == 0) AS(fgrp + g * 16, s);
    }
}

// ---------------------------------------------------------------------------
// Layer 1: grid 128 = dir(2) x batch-quarter(4) x gate-group(16).
// M=32 rows, N=64 cols, K=768 ([h1_prev|h0f|h0b]). Waves split N by gate.
// h0 part of GEMM pre-poll on cached loads; racy h1_prev staged into LDS
// once per block (atomic u64 loads), fragments via ds_read_b128.
// 24 B-fragments = 96 VGPRs, loaded once (now truly resident).
// ---------------------------------------------------------------------------
__global__ __launch_bounds__(256, 1)
__attribute__((amdgpu_waves_per_eu(1, 1)))
void k_l1(
    const float* __restrict__ wih1, const float* __restrict__ whh1,
    const float* __restrict__ bih1, const float* __restrict__ bhh1,
    bf16* __restrict__ h0, bf16* __restrict__ h1,
    float* __restrict__ pooled, int* __restrict__ flags)
{
    __shared__ float Gs[4][32][17];                    // gate exchange (pad 17)
    __shared__ __align__(16) bf16 Hs[32][20];          // h repack (pad 20)
    __shared__ __align__(16) bf16 As1[32][264];        // h1_prev stage (pad 264)

    const int blk = blockIdx.x;
    const int dir = blk >> 6, bq = (blk >> 4) & 3, g = blk & 15;
    const int tid = threadIdx.x, wave = tid >> 6, lane = tid & 63;
    const int l15 = lane & 15, q = lane >> 4;
    const int n = dir * 1024 + wave * 256 + g * 16 + l15;  // wave = gate

    // B fragments: 24 x 4 VGPR = 96 VGPRs. kt<8 -> Whh1; 8..15 -> h0f part
    // of Wih1; 16..23 -> h0b part.
    bf16x8 Bf[24];
#pragma unroll
    for (int kt = 0; kt < 24; ++kt) {
        const int k = kt * 32 + q * 8;
        const float* src = (kt < 8) ? (whh1 + (size_t)n * 256 + k)
                                    : (wih1 + (size_t)n * 512 + (k - 256));
        f32x4 aa = *(const f32x4*)src;
        f32x4 bb = *(const f32x4*)(src + 4);
        bf16x8 f;
        f[0] = (bf16)aa[0]; f[1] = (bf16)aa[1]; f[2] = (bf16)aa[2]; f[3] = (bf16)aa[3];
        f[4] = (bf16)bb[0]; f[5] = (bf16)bb[1]; f[6] = (bf16)bb[2]; f[7] = (bf16)bb[3];
        Bf[kt] = f;
    }
    const float biasw = bih1[n] + bhh1[n];
    const int r0 = tid >> 4, colu = tid & 15;     // update: rows r0, r0+16
    float cst[2] = {0.f, 0.f}, pool[2] = {0.f, 0.f};
    int* fgrp = flags + (dir * 4 + bq) * 256;
    int budget = 30000000;

#pragma unroll 1
    for (int s = 1; s <= T_SEQ; ++s) {
        const int slotf = dir ? (513 - s) : s;     // h0 fwd slot for time t
        const int slotb = dir ? s : (513 - s);     // h0 bwd slot for time t

        // --- pre-poll: h0 contribution (non-racy, cached) ---
        f32x4 acc0 = {biasw, biasw, biasw, biasw};
        f32x4 acc1 = acc0;
        const bf16* f0 = h0 + ((size_t)slotf * BATCH + bq * 32 + l15) * HID + q * 8;
        const bf16* b0 = h0 + ((size_t)(513 + slotb) * BATCH + bq * 32 + l15) * HID + q * 8;
#pragma unroll
        for (int kt = 0; kt < 8; ++kt) {
            const bf16x8 af0 = *(const bf16x8*)(f0 + kt * 32);
            const bf16x8 af1 = *(const bf16x8*)(f0 + 16 * HID + kt * 32);
            acc0 = MFMA16(af0, Bf[8 + kt], acc0);
            acc1 = MFMA16(af1, Bf[8 + kt], acc1);
        }
#pragma unroll
        for (int kt = 0; kt < 8; ++kt) {
            const bf16x8 ab0 = *(const bf16x8*)(b0 + kt * 32);
            const bf16x8 ab1 = *(const bf16x8*)(b0 + 16 * HID + kt * 32);
            acc0 = MFMA16(ab0, Bf[16 + kt], acc0);
            acc1 = MFMA16(ab1, Bf[16 + kt], acc1);
        }

        // --- poll producers ---
        if (lane < 16) {
            const int need = s - 1;
            while (AL(fgrp + lane * 16) < need) {
                if (--budget < 0) break;
            }
        }
        asm volatile("" ::: "memory");

        // --- stage racy h1_prev [32][256] into LDS (atomic u64 loads) ---
        {
            const u64* hb = (const u64*)(h1 + ((size_t)(dir * 2 + ((s - 1) & 1)) * BATCH
                                               + bq * 32) * HID);
#pragma unroll
            for (int i = 0; i < 4; ++i) {
                const int chunk = tid + 256 * i;         // 0..1023 (16B chunks)
                const int row = chunk >> 5, cc = chunk & 31;
                const u64 lo = AL(hb + (size_t)row * 64 + cc * 2);
                const u64 hi = AL(hb + (size_t)row * 64 + cc * 2 + 1);
                u64x2 t2; t2[0] = lo; t2[1] = hi;
                *(bf16x8*)(&As1[row][cc * 8]) = __builtin_bit_cast(bf16x8, t2);
            }
        }
        __syncthreads();

        // --- h1_prev GEMM from LDS: 2 M-tiles x 8 K-steps ---
#pragma unroll
        for (int kt = 0; kt < 8; ++kt) {
            const bf16x8 a0 = *(const bf16x8*)(&As1[l15][kt * 32 + q * 8]);
            const bf16x8 a1 = *(const bf16x8*)(&As1[16 + l15][kt * 32 + q * 8]);
            acc0 = MFMA16(a0, Bf[kt], acc0);
            acc1 = MFMA16(a1, Bf[kt], acc1);
        }

        // --- gate exchange via LDS ---
#pragma unroll
        for (int r = 0; r < 4; ++r) {
            Gs[wave][q * 4 + r][l15]      = acc0[r];
            Gs[wave][16 + q * 4 + r][l15] = acc1[r];
        }
        __syncthreads();

        // --- cell update: rows r0, r0+16 of hidden unit colu ---
#pragma unroll
        for (int rr = 0; rr < 2; ++rr) {
            const int r = r0 + rr * 16;
            const float iv = fsig(Gs[0][r][colu]);
            const float fv = fsig(Gs[1][r][colu]);
            const float gv = ftanh(Gs[2][r][colu]);
            const float ov = fsig(Gs[3][r][colu]);
            cst[rr] = fv * cst[rr] + iv * gv;
            const float hv = ov * ftanh(cst[rr]);
            pool[rr] += hv;
            Hs[r][colu] = (bf16)hv;
        }
        __syncthreads();
        // 4B agent-atomic store per thread
        {
            const int lrow = tid >> 3, c2 = (tid & 7) * 2;
            const u32 hv4 = *(const u32*)&Hs[lrow][c2];
            u32* dst = (u32*)(h1 + ((size_t)(dir * 2 + (s & 1)) * BATCH + bq * 32 + lrow) * HID
                              + g * 16 + c2);
            AS(dst, hv4);
        }
        __syncthreads();                       // drains vmcnt before flag
        if (tid == 0) AS(fgrp + g * 16, s);
    }
    // mean pool epilogue
#pragma unroll
    for (int rr = 0; rr < 2; ++rr) {
        const int r = r0 + rr * 16;
        pooled[((size_t)dir * BATCH + bq * 32 + r) * HID + g * 16 + colu] =
            pool[rr] * (1.0f / 512.0f);
    }
}

// ---------------------------------------------------------------------------
__global__ void k_fc(const float* __restrict__ pooled, const float* __restrict__ fcw,
                     const float* __restrict__ fcb, float* __restrict__ out)
{
    const int b = blockIdx.x;            // 128 blocks, 64 threads
    const int lane = threadIdx.x;
    float s0 = 0.f, s1 = 0.f;
#pragma unroll
    for (int jj = 0; jj < 8; ++jj) {
        const int jx = lane + jj * 64;   // 0..511
        const float p = (jx < 256) ? pooled[(size_t)b * 256 + jx]
                                   : pooled[32768 + (size_t)b * 256 + (jx - 256)];
        s0 += p * fcw[jx];
        s1 += p * fcw[512 + jx];
    }
#pragma unroll
    for (int off = 32; off > 0; off >>= 1) {
        s0 += __shfl_down(s0, off);
        s1 += __shfl_down(s1, off);
    }
    if (lane == 0) {
        out[b * 2 + 0] = s0 + fcb[0];
        out[b * 2 + 1] = s1 + fcb[1];
    }
}

// ---------------------------------------------------------------------------
extern "C" void kernel_launch(void* const* d_in, const int* in_sizes, int n_in,
                              void* d_out, int out_size, void* d_ws, size_t ws_size,
                              hipStream_t stream)
{
    const float* x    = (const float*)d_in[0];
    const float* wih0 = (const float*)d_in[1];
    const float* whh0 = (const float*)d_in[2];
    const float* bih0 = (const float*)d_in[3];
    const float* bhh0 = (const float*)d_in[4];
    const float* wih1 = (const float*)d_in[5];
    const float* whh1 = (const float*)d_in[6];
    const float* bih1 = (const float*)d_in[7];
    const float* bhh1 = (const float*)d_in[8];
    const float* fcw  = (const float*)d_in[9];
    const float* fcb  = (const float*)d_in[10];
    float* out = (float*)d_out;

    char* ws = (char*)d_ws;
    bf16* h0      = (bf16*)ws;
    bf16* h1      = (bf16*)(ws + H0_BYTES);
    float* pooled = (float*)(ws + H0_BYTES + H1_BYTES);
    int* flags0   = (int*)(ws + FL0_OFF);
    int* flags1   = (int*)(ws + FL1_OFF);

    k_init<<<dim3(64), dim3(256), 0, stream>>>((unsigned int*)ws, flags0, flags1);
    k_l0<<<dim3(64), dim3(256), 0, stream>>>(x, wih0, whh0, bih0, bhh0, h0, flags0);
    k_l1<<<dim3(128), dim3(256), 0, stream>>>(wih1, whh1, bih1, bhh1, h0, h1, pooled, flags1);
    k_fc<<<dim3(128), dim3(64), 0, stream>>>(pooled, fcw, fcb, out);
}